// Round 8
// baseline (376.585 us; speedup 1.0000x reference)
//
#include <hip/hip_runtime.h>

typedef float  f32x4 __attribute__((ext_vector_type(4)));
typedef short  s16x8 __attribute__((ext_vector_type(8)));
typedef unsigned short u16x8 __attribute__((ext_vector_type(8)));

#define NROWS 4096
#define ALPHA_LR 0.2f
#define SCALE 0.0625f

static __device__ __forceinline__ unsigned short bf16_rne(float x) {
    unsigned u = __float_as_uint(x);
    u += 0x7fffu + ((u >> 16) & 1u);
    return (unsigned short)(u >> 16);
}
static __device__ __forceinline__ unsigned short bf16_trunc(float x) {
    return (unsigned short)(__float_as_uint(x) >> 16);
}
static __device__ __forceinline__ float bf2f(unsigned short h) {
    return __uint_as_float(((unsigned)h) << 16);
}
static __device__ __forceinline__ float wmax16(float v) {
#pragma unroll
    for (int o = 8; o; o >>= 1) v = fmaxf(v, __shfl_xor(v, o, 16));
    return v;
}
static __device__ __forceinline__ float wsum16(float v) {
#pragma unroll
    for (int o = 8; o; o >>= 1) v += __shfl_xor(v, o, 16);
    return v;
}

// ---------------------------------------------------------------------------
// Convert W (512x256) and Wqkv_w (768x256) to bf16 hi/lo.
// ---------------------------------------------------------------------------
__global__ __launch_bounds__(256) void wprep(
    const float* __restrict__ W, const float* __restrict__ Wq,
    unsigned short* __restrict__ Whi, unsigned short* __restrict__ Wlo,
    unsigned short* __restrict__ Qhi, unsigned short* __restrict__ Qlo)
{
    int i = blockIdx.x * 256 + threadIdx.x;
    if (i < 131072) {
        float v = W[i];
        unsigned short hh = bf16_trunc(v);
        Whi[i] = hh; Wlo[i] = bf16_rne(v - bf2f(hh));
    }
    if (i < 196608) {
        float v = Wq[i];
        unsigned short hh = bf16_trunc(v);
        Qhi[i] = hh; Qlo[i] = bf16_rne(v - bf2f(hh));
    }
}

// ---------------------------------------------------------------------------
// MFMA GEMM, 3-term bf16 hi/lo split (unchanged).
// ---------------------------------------------------------------------------
template <int EPI, bool BIAS>
__global__ __launch_bounds__(256) void gemm_mfma(
    const float* __restrict__ A,
    const unsigned short* __restrict__ Bhi, const unsigned short* __restrict__ Blo,
    const float* __restrict__ bias,
    float* __restrict__ C, unsigned short* __restrict__ o0,
    unsigned short* __restrict__ o1, unsigned short* __restrict__ o2,
    int M, int Nn, int K)
{
    __shared__ unsigned short Ah[64][40];
    __shared__ unsigned short Al[64][40];
    __shared__ unsigned short Bh[64][40];
    __shared__ unsigned short Bl[64][40];

    const int tid = threadIdx.x;
    const int w = tid >> 6;
    const int ln = tid & 63;
    const int l15 = ln & 15;
    const int lhi = ln >> 4;
    const int bm = blockIdx.y * 64;
    const int bn = blockIdx.x * 64;
    const int sm = tid >> 2;
    const int sk = (tid & 3) * 8;

    f32x4 acc[4];
#pragma unroll
    for (int cf = 0; cf < 4; ++cf) acc[cf] = (f32x4){0.f, 0.f, 0.f, 0.f};

    const float* arow = &A[(size_t)(bm + sm) * K];
    const unsigned short* bhrow = &Bhi[(size_t)(bn + sm) * K];
    const unsigned short* blrow = &Blo[(size_t)(bn + sm) * K];

    float4 a0r = *(const float4*)(arow + sk);
    float4 a1r = *(const float4*)(arow + sk + 4);
    uint4 bhr = *(const uint4*)(bhrow + sk);
    uint4 blr = *(const uint4*)(blrow + sk);

    for (int k0 = 0; k0 < K; k0 += 32) {
        float vv[8] = {a0r.x, a0r.y, a0r.z, a0r.w, a1r.x, a1r.y, a1r.z, a1r.w};
        unsigned hp[4], lp[4];
#pragma unroll
        for (int q = 0; q < 4; ++q) {
            unsigned short h0 = bf16_trunc(vv[q * 2]);
            unsigned short h1 = bf16_trunc(vv[q * 2 + 1]);
            unsigned short l0 = bf16_rne(vv[q * 2] - bf2f(h0));
            unsigned short l1 = bf16_rne(vv[q * 2 + 1] - bf2f(h1));
            hp[q] = (unsigned)h0 | ((unsigned)h1 << 16);
            lp[q] = (unsigned)l0 | ((unsigned)l1 << 16);
        }
        __syncthreads();
        *(uint4*)&Ah[sm][sk] = make_uint4(hp[0], hp[1], hp[2], hp[3]);
        *(uint4*)&Al[sm][sk] = make_uint4(lp[0], lp[1], lp[2], lp[3]);
        *(uint4*)&Bh[sm][sk] = bhr;
        *(uint4*)&Bl[sm][sk] = blr;
        const int kn = (k0 + 32 < K) ? k0 + 32 : 0;
        a0r = *(const float4*)(arow + kn + sk);
        a1r = *(const float4*)(arow + kn + sk + 4);
        bhr = *(const uint4*)(bhrow + kn + sk);
        blr = *(const uint4*)(blrow + kn + sk);
        __syncthreads();
        s16x8 ah = *(const s16x8*)&Ah[w * 16 + l15][lhi * 8];
        s16x8 al2 = *(const s16x8*)&Al[w * 16 + l15][lhi * 8];
        __builtin_amdgcn_s_setprio(1);
#pragma unroll
        for (int cf = 0; cf < 4; ++cf) {
            s16x8 bh = *(const s16x8*)&Bh[cf * 16 + l15][lhi * 8];
            s16x8 bl = *(const s16x8*)&Bl[cf * 16 + l15][lhi * 8];
            acc[cf] = __builtin_amdgcn_mfma_f32_16x16x32_bf16(ah, bh, acc[cf], 0, 0, 0);
            acc[cf] = __builtin_amdgcn_mfma_f32_16x16x32_bf16(ah, bl, acc[cf], 0, 0, 0);
            acc[cf] = __builtin_amdgcn_mfma_f32_16x16x32_bf16(al2, bh, acc[cf], 0, 0, 0);
        }
        __builtin_amdgcn_s_setprio(0);
    }

#pragma unroll
    for (int cf = 0; cf < 4; ++cf) {
        const int col = bn + cf * 16 + l15;
        float bv = BIAS ? bias[col] : 0.0f;
#pragma unroll
        for (int r = 0; r < 4; ++r) {
            const int row = bm + w * 16 + lhi * 4 + r;
            float v = acc[cf][r] + bv;
            if (EPI == 1) {
                C[(size_t)row * Nn + col] = v;
                o0[(size_t)col * NROWS + row] = bf16_rne(v);
            } else if (EPI == 2) {
                if (col < 256)      o0[(size_t)row * 256 + col] = bf16_rne(v);
                else if (col < 512) o1[(size_t)row * 256 + (col - 256)] = bf16_rne(v);
                else                o2[(size_t)(col - 512) * NROWS + row] = bf16_rne(v);
            } else {
                unsigned short hh = bf16_trunc(v);
                o0[(size_t)row * Nn + col] = hh;
                o1[(size_t)row * Nn + col] = bf16_rne(v - bf2f(hh));
            }
        }
    }
}

// ---------------------------------------------------------------------------
// p1 = Wh @ a[:256], p2 = Wh @ a[256:]
// ---------------------------------------------------------------------------
__global__ __launch_bounds__(256) void compute_p(
    const float* __restrict__ Wh, const float* __restrict__ a,
    float* __restrict__ p1, float* __restrict__ p2)
{
    const int row = blockIdx.x * 16 + (threadIdx.x >> 4);
    const int c = threadIdx.x & 15;
    float s1 = 0.f, s2 = 0.f;
    for (int f = c; f < 256; f += 16) {
        float w = Wh[(size_t)row * 256 + f];
        s1 += w * a[f];
        s2 += w * a[256 + f];
    }
    s1 = wsum16(s1);
    s2 = wsum16(s2);
    if (c == 0) { p1[row] = s1; p2[row] = s2; }
}

// ---------------------------------------------------------------------------
// Global max of p2 (single block).
// ---------------------------------------------------------------------------
__global__ __launch_bounds__(256) void p2max_kernel(
    const float* __restrict__ p2, float* __restrict__ p2m)
{
    __shared__ float red[4];
    const int tid = threadIdx.x;
    float v = -3.0e38f;
#pragma unroll
    for (int k = 0; k < 16; ++k) v = fmaxf(v, p2[tid + k * 256]);
#pragma unroll
    for (int o = 32; o; o >>= 1) v = fmaxf(v, __shfl_xor(v, o, 64));
    if ((tid & 63) == 0) red[tid >> 6] = v;
    __syncthreads();
    if (tid == 0) p2m[0] = fmaxf(fmaxf(red[0], red[1]), fmaxf(red[2], red[3]));
}

// ---------------------------------------------------------------------------
// norms1/norms2: Cauchy-Schwarz bound M[i][h] = ||q_i||*max||k||/16.
// ---------------------------------------------------------------------------
__global__ __launch_bounds__(256) void norms1(
    const unsigned short* __restrict__ qh, const unsigned short* __restrict__ kh,
    float* __restrict__ qn2, float* __restrict__ knp)
{
    __shared__ float kn[16][4];
    const int tid = threadIdx.x;
    const int r16 = tid >> 4;
    const int c = tid & 15;
    const int i = blockIdx.x * 16 + r16;
#pragma unroll
    for (int h = 0; h < 4; ++h) {
        float sq = 0.f, sk = 0.f;
#pragma unroll
        for (int d = 0; d < 4; ++d) {
            float qv = bf2f(qh[(size_t)i * 256 + h * 64 + c + d * 16]);
            float kv = bf2f(kh[(size_t)i * 256 + h * 64 + c + d * 16]);
            sq += qv * qv; sk += kv * kv;
        }
        sq = wsum16(sq); sk = wsum16(sk);
        if (c == 0) { qn2[i * 4 + h] = sq; kn[r16][h] = sk; }
    }
    __syncthreads();
    if (tid < 4) {
        float m = 0.f;
#pragma unroll
        for (int r = 0; r < 16; ++r) m = fmaxf(m, kn[r][tid]);
        knp[blockIdx.x * 4 + tid] = m;
    }
}

__global__ __launch_bounds__(256) void norms2(
    const float* __restrict__ qn2, const float* __restrict__ knp,
    float* __restrict__ Mb)
{
    __shared__ float red[4][4];
    __shared__ float kmax[4];
    const int tid = threadIdx.x;
    float v[4];
#pragma unroll
    for (int h = 0; h < 4; ++h) v[h] = knp[tid * 4 + h];
#pragma unroll
    for (int h = 0; h < 4; ++h)
#pragma unroll
        for (int o = 32; o; o >>= 1) v[h] = fmaxf(v[h], __shfl_xor(v[h], o, 64));
    if ((tid & 63) == 0) {
#pragma unroll
        for (int h = 0; h < 4; ++h) red[tid >> 6][h] = v[h];
    }
    __syncthreads();
    if (tid < 4)
        kmax[tid] = fmaxf(fmaxf(red[0][tid], red[1][tid]), fmaxf(red[2][tid], red[3][tid]));
    __syncthreads();
    const int i = blockIdx.x * 256 + tid;
#pragma unroll
    for (int h = 0; h < 4; ++h)
        Mb[i * 4 + h] = sqrtf(qn2[i * 4 + h] * kmax[h]) * SCALE;
}

// ---------------------------------------------------------------------------
// zsum v2: swapped QK (mfma(K,Q)) -> lane-local z for i = lane&15, all 4
// heads per wave, waves take interleaved j-tiles, NO in-loop barriers.
// grid = 256 rowtiles x 4 chunks. e formula identical to pvds.
// ---------------------------------------------------------------------------
__global__ __launch_bounds__(256) void zsum_kernel(
    const unsigned short* __restrict__ qh_g, const unsigned short* __restrict__ kh_g,
    const float* __restrict__ Mb, float* __restrict__ zpart)
{
    __shared__ float zred[4][4][16];   // [wave][head][i]
    const int tid = threadIdx.x;
    const int w = tid >> 6;
    const int ln = tid & 63;
    const int l15 = ln & 15;
    const int lhi = ln >> 4;
    const int rt = blockIdx.x & 255;
    const int ch = blockIdx.x >> 8;
    const int i0 = rt * 16;
    const int jb = ch * 1024;

    s16x8 qB[4][2];
#pragma unroll
    for (int h = 0; h < 4; ++h)
#pragma unroll
        for (int ks = 0; ks < 2; ++ks)
            qB[h][ks] = *(const s16x8*)(qh_g + (size_t)(i0 + l15) * 256 + h * 64 + ks * 32 + lhi * 8);
    float Mv[4];
#pragma unroll
    for (int h = 0; h < 4; ++h) Mv[h] = Mb[(i0 + l15) * 4 + h];

    float z[4] = {0.f, 0.f, 0.f, 0.f};
    const unsigned short* kpB = kh_g + (size_t)l15 * 256 + lhi * 8;

    for (int tt = 0; tt < 8; ++tt) {
        const int j0 = jb + (tt * 4 + w) * 32;
#pragma unroll
        for (int h = 0; h < 4; ++h) {
            s16x8 kA00 = *(const s16x8*)(kpB + (size_t)j0 * 256 + h * 64);
            s16x8 kA01 = *(const s16x8*)(kpB + (size_t)j0 * 256 + h * 64 + 32);
            s16x8 kA10 = *(const s16x8*)(kpB + (size_t)(j0 + 16) * 256 + h * 64);
            s16x8 kA11 = *(const s16x8*)(kpB + (size_t)(j0 + 16) * 256 + h * 64 + 32);
            f32x4 acc0 = {0.f, 0.f, 0.f, 0.f};
            f32x4 acc1 = {0.f, 0.f, 0.f, 0.f};
            acc0 = __builtin_amdgcn_mfma_f32_16x16x32_bf16(kA00, qB[h][0], acc0, 0, 0, 0);
            acc0 = __builtin_amdgcn_mfma_f32_16x16x32_bf16(kA01, qB[h][1], acc0, 0, 0, 0);
            acc1 = __builtin_amdgcn_mfma_f32_16x16x32_bf16(kA10, qB[h][0], acc1, 0, 0, 0);
            acc1 = __builtin_amdgcn_mfma_f32_16x16x32_bf16(kA11, qB[h][1], acc1, 0, 0, 0);
#pragma unroll
            for (int r = 0; r < 4; ++r) {
                z[h] += __expf(fmaf(acc0[r], SCALE, -Mv[h]));
                z[h] += __expf(fmaf(acc1[r], SCALE, -Mv[h]));
            }
        }
    }
#pragma unroll
    for (int h = 0; h < 4; ++h) {
        float v = z[h];
        v += __shfl_xor(v, 16);
        v += __shfl_xor(v, 32);
        if (ln < 16) zred[w][h][ln] = v;
    }
    __syncthreads();
    if (tid < 64) {
        int hh = tid >> 4, row = tid & 15;
        float zz = ((zred[0][hh][row] + zred[1][hh][row]) + zred[2][hh][row]) + zred[3][hh][row];
        zpart[((size_t)(i0 + row) * 4 + hh) * 4 + ch] = zz;
    }
}

// ---------------------------------------------------------------------------
// pvds v2: one wave handles ALL 4 heads of its (rowtile, j-tile); swapped QK
// makes dsum an in-register cross-head sum (no barrier). Dots transpose for
// PV via per-wave private LDS (same-wave lgkmcnt only). Waves interleave
// tiles; pacc reduced across waves once at the end.
// grid = 256 rowtiles x 4 chunks.
// ---------------------------------------------------------------------------
__global__ __launch_bounds__(256) void pvds_kernel(
    const unsigned short* __restrict__ qh_g, const unsigned short* __restrict__ kh_g,
    const unsigned short* __restrict__ vth_g,
    const float* __restrict__ Mb, const float* __restrict__ zpart,
    unsigned short* __restrict__ dsum_g, unsigned short* __restrict__ pacc_o)
{
    enum { DOTS = 0, MIZ = 20480, SMEMSZ = 20992 };   // dots: 4 waves x 4 heads x 16 x 80B
    __shared__ __align__(16) char smem[SMEMSZ];
    float* smF = (float*)smem;                         // end-reduction overlays dots

    const int tid = threadIdx.x;
    const int w = tid >> 6;
    const int ln = tid & 63;
    const int l15 = ln & 15;
    const int lhi = ln >> 4;
    const int rt = blockIdx.x & 255;
    const int ch = blockIdx.x >> 8;
    const int i0 = rt * 16;
    const int jb = ch * 1024;

    if (tid < 64) {
        int hh = tid >> 4, row = tid & 15;
        const float* zb = zpart + ((size_t)(i0 + row) * 4 + hh) * 4;
        float z = ((zb[0] + zb[1]) + zb[2]) + zb[3];
        float* fl = (float*)(smem + MIZ);
        fl[(hh * 16 + row) * 2] = Mb[(i0 + row) * 4 + hh];
        fl[(hh * 16 + row) * 2 + 1] = 1.0f / z;
    }

    s16x8 qB[4][2];
#pragma unroll
    for (int h = 0; h < 4; ++h)
#pragma unroll
        for (int ks = 0; ks < 2; ++ks)
            qB[h][ks] = *(const s16x8*)(qh_g + (size_t)(i0 + l15) * 256 + h * 64 + ks * 32 + lhi * 8);
    __syncthreads();

    float Mv[4], izv[4];
#pragma unroll
    for (int h = 0; h < 4; ++h) {
        Mv[h]  = ((const float*)(smem + MIZ))[(h * 16 + l15) * 2];
        izv[h] = ((const float*)(smem + MIZ))[(h * 16 + l15) * 2 + 1];
    }

    const unsigned short* kpB = kh_g + (size_t)l15 * 256 + lhi * 8;
    const unsigned short* vpB = vth_g + (size_t)l15 * 4096 + lhi * 8;
    // per-wave dots region
    char* dots_w = smem + DOTS + w * 5120;
    const int dwr0 = l15 * 80 + lhi * 8;        // write base (nt=0), +32 for nt=1
    const int drd  = l15 * 80 + lhi * 16;       // b128 read base

    f32x4 pacc[4][4];
#pragma unroll
    for (int h = 0; h < 4; ++h)
#pragma unroll
        for (int nt2 = 0; nt2 < 4; ++nt2) pacc[h][nt2] = (f32x4){0.f, 0.f, 0.f, 0.f};

    for (int tt = 0; tt < 8; ++tt) {
        const int j0 = jb + (tt * 4 + w) * 32;
        float dsA0[4] = {0.f, 0.f, 0.f, 0.f};
        float dsA1[4] = {0.f, 0.f, 0.f, 0.f};

        // ---- QK (all heads) + e + dots->LDS, dsum in-register ----
#pragma unroll
        for (int h = 0; h < 4; ++h) {
            s16x8 kA00 = *(const s16x8*)(kpB + (size_t)j0 * 256 + h * 64);
            s16x8 kA01 = *(const s16x8*)(kpB + (size_t)j0 * 256 + h * 64 + 32);
            s16x8 kA10 = *(const s16x8*)(kpB + (size_t)(j0 + 16) * 256 + h * 64);
            s16x8 kA11 = *(const s16x8*)(kpB + (size_t)(j0 + 16) * 256 + h * 64 + 32);
            f32x4 acc0 = {0.f, 0.f, 0.f, 0.f};
            f32x4 acc1 = {0.f, 0.f, 0.f, 0.f};
            acc0 = __builtin_amdgcn_mfma_f32_16x16x32_bf16(kA00, qB[h][0], acc0, 0, 0, 0);
            acc0 = __builtin_amdgcn_mfma_f32_16x16x32_bf16(kA01, qB[h][1], acc0, 0, 0, 0);
            acc1 = __builtin_amdgcn_mfma_f32_16x16x32_bf16(kA10, qB[h][0], acc1, 0, 0, 0);
            acc1 = __builtin_amdgcn_mfma_f32_16x16x32_bf16(kA11, qB[h][1], acc1, 0, 0, 0);
            float e0[4], e1[4];
#pragma unroll
            for (int r = 0; r < 4; ++r) {
                e0[r] = __expf(fmaf(acc0[r], SCALE, -Mv[h])) * izv[h];
                e1[r] = __expf(fmaf(acc1[r], SCALE, -Mv[h])) * izv[h];
                dsA0[r] += e0[r];
                dsA1[r] += e1[r];
            }
            ushort4 p0, p1;
            p0.x = bf16_rne(e0[0]); p0.y = bf16_rne(e0[1]); p0.z = bf16_rne(e0[2]); p0.w = bf16_rne(e0[3]);
            p1.x = bf16_rne(e1[0]); p1.y = bf16_rne(e1[1]); p1.z = bf16_rne(e1[2]); p1.w = bf16_rne(e1[3]);
            *(ushort4*)(dots_w + h * 1280 + dwr0)      = p0;
            *(ushort4*)(dots_w + h * 1280 + dwr0 + 32) = p1;
        }

        // ---- dsum -> global (bf16, packed) ----
        {
            ushort4 d0, d1;
            d0.x = bf16_rne(dsA0[0]); d0.y = bf16_rne(dsA0[1]); d0.z = bf16_rne(dsA0[2]); d0.w = bf16_rne(dsA0[3]);
            d1.x = bf16_rne(dsA1[0]); d1.y = bf16_rne(dsA1[1]); d1.z = bf16_rne(dsA1[2]); d1.w = bf16_rne(dsA1[3]);
            unsigned short* db = dsum_g + (size_t)(i0 + l15) * 4096 + j0 + lhi * 4;
            *(ushort4*)(db)      = d0;
            *(ushort4*)(db + 16) = d1;
        }

        // ---- PV (same-wave LDS read, no barrier) ----
#pragma unroll
        for (int h = 0; h < 4; ++h) {
            s16x8 dA = *(const s16x8*)(dots_w + h * 1280 + drd);
#pragma unroll
            for (int nt2 = 0; nt2 < 4; ++nt2) {
                s16x8 vB = *(const s16x8*)(vpB + (size_t)(h * 64 + nt2 * 16) * 4096 + j0);
                pacc[h][nt2] = __builtin_amdgcn_mfma_f32_16x16x32_bf16(dA, vB, pacc[h][nt2], 0, 0, 0);
            }
        }
    }

    // ---- end: reduce pacc across the 4 waves, one head per round ----
    const size_t pbase = (size_t)(rt * 4 + ch) * 4096;
#pragma unroll
    for (int h = 0; h < 4; ++h) {
        __syncthreads();
#pragma unroll
        for (int nt2 = 0; nt2 < 4; ++nt2)
#pragma unroll
            for (int r = 0; r < 4; ++r)
                smF[w * 1024 + (lhi * 4 + r) * 64 + nt2 * 16 + l15] = pacc[h][nt2][r];
        __syncthreads();
        const int ri = tid >> 4;
        const int db = (tid & 15) * 4;
        float4 s0 = *(const float4*)&smF[0 * 1024 + ri * 64 + db];
        float4 s1 = *(const float4*)&smF[1 * 1024 + ri * 64 + db];
        float4 s2 = *(const float4*)&smF[2 * 1024 + ri * 64 + db];
        float4 s3 = *(const float4*)&smF[3 * 1024 + ri * 64 + db];
        ushort4 o;
        o.x = bf16_rne(s0.x + s1.x + s2.x + s3.x);
        o.y = bf16_rne(s0.y + s1.y + s2.y + s3.y);
        o.z = bf16_rne(s0.z + s1.z + s2.z + s3.z);
        o.w = bf16_rne(s0.w + s1.w + s2.w + s3.w);
        *(ushort4*)(pacc_o + pbase + ri * 256 + h * 64 + db) = o;
    }
}

// ---------------------------------------------------------------------------
// outer v2: LDS-free, barrier-free. Each lane computes ptil for
// (i = lane&15, j = lhi*8..+7) — exactly the MFMA A-fragment. 4 waves = 4
// f-slices (redundant ptil, no coordination). grid = 256 rowtiles x 4 chunks.
// ---------------------------------------------------------------------------
__global__ __launch_bounds__(256) void outer_kernel(
    const unsigned short* __restrict__ wht_g, const unsigned short* __restrict__ dsum_g,
    const float* __restrict__ p1g, const float* __restrict__ p2g,
    const float* __restrict__ p2m, const int* __restrict__ adj,
    unsigned short* __restrict__ wacc_o, float* __restrict__ Lp_o)
{
    const int tid = threadIdx.x;
    const int w = tid >> 6;
    const int ln = tid & 63;
    const int l15 = ln & 15;
    const int lhi = ln >> 4;
    const int rt = blockIdx.x & 255;
    const int ch = blockIdx.x >> 8;
    const int i0 = rt * 16;
    const int jb = ch * 1024;
    const int i = i0 + l15;

    const float p1v = p1g[i];
    float Mfix;
    {
        float s = p1v + p2m[0];
        Mfix = (s > 0.f ? s : ALPHA_LR * s) + 4.0f;
    }

    const int* adjB = adj + (size_t)i * 4096 + lhi * 8;
    const unsigned short* dsB = dsum_g + (size_t)i * 4096 + lhi * 8;
    const float* p2B = p2g + lhi * 8;
    const unsigned short* whB = wht_g + lhi * 8;

    // prefetch tile 0
    int4 a0 = *(const int4*)(adjB + jb);
    int4 a1 = *(const int4*)(adjB + jb + 4);
    u16x8 ds = *(const u16x8*)(dsB + jb);
    float4 q0 = *(const float4*)(p2B + jb);
    float4 q1 = *(const float4*)(p2B + jb + 4);
    s16x8 wf[4];
#pragma unroll
    for (int nt = 0; nt < 4; ++nt)
        wf[nt] = *(const s16x8*)(whB + (size_t)(w * 64 + nt * 16 + l15) * 4096 + jb);

    f32x4 acc[4];
#pragma unroll
    for (int nt = 0; nt < 4; ++nt) acc[nt] = (f32x4){0.f, 0.f, 0.f, 0.f};
    float Lacc = 0.0f;

    for (int t = 0; t < 32; ++t) {
        const int jn = jb + ((t + 1) & 31) * 32;

        float pr[8];
        {
            int am[8] = {a0.x, a0.y, a0.z, a0.w, a1.x, a1.y, a1.z, a1.w};
            float pv[8] = {q0.x, q0.y, q0.z, q0.w, q1.x, q1.y, q1.z, q1.w};
#pragma unroll
            for (int k = 0; k < 8; ++k) {
                float e = p1v + pv[k];
                e = e > 0.f ? e : ALPHA_LR * e;
                float arg = e + bf2f((unsigned short)ds[k]) - Mfix;
                pr[k] = (am[k] > 0) ? __expf(arg) : 0.f;
                Lacc += pr[k];
            }
        }
        // prefetch scalars t+1
        a0 = *(const int4*)(adjB + jn);
        a1 = *(const int4*)(adjB + jn + 4);
        ds = *(const u16x8*)(dsB + jn);
        q0 = *(const float4*)(p2B + jn);
        q1 = *(const float4*)(p2B + jn + 4);

        // A fragment from registers
        s16x8 pA;
#pragma unroll
        for (int k = 0; k < 8; ++k) pA[k] = (short)bf16_rne(pr[k]);

        __builtin_amdgcn_s_setprio(1);
#pragma unroll
        for (int nt = 0; nt < 4; ++nt)
            acc[nt] = __builtin_amdgcn_mfma_f32_16x16x32_bf16(pA, wf[nt], acc[nt], 0, 0, 0);
        __builtin_amdgcn_s_setprio(0);

        // prefetch Wh frags t+1
#pragma unroll
        for (int nt = 0; nt < 4; ++nt)
            wf[nt] = *(const s16x8*)(whB + (size_t)(w * 64 + nt * 16 + l15) * 4096 + jn);
    }

    Lacc += __shfl_xor(Lacc, 16);
    Lacc += __shfl_xor(Lacc, 32);
    if (w == 0 && ln < 16) Lp_o[(size_t)(rt * 4 + ch) * 16 + l15] = Lacc;

    const size_t wbase = (size_t)(rt * 4 + ch) * 4096;
#pragma unroll
    for (int nt = 0; nt < 4; ++nt)
#pragma unroll
        for (int r = 0; r < 4; ++r)
            wacc_o[wbase + (lhi * 4 + r) * 256 + w * 64 + nt * 16 + l15] = bf16_rne(acc[nt][r]);
}

// ---------------------------------------------------------------------------
// Merge: sum 4 chunks, Wh0 row softmax, normalize, elu, store.
// ---------------------------------------------------------------------------
__global__ __launch_bounds__(256) void merge_kernel(
    const unsigned short* __restrict__ pacc_b, const unsigned short* __restrict__ wacc_b,
    const float* __restrict__ Lp, float* __restrict__ out)
{
    const int rt = blockIdx.x;
    const int tid = threadIdx.x;
    const int row = tid >> 4;
    const int cg = tid & 15;

    float L = 0.f;
#pragma unroll
    for (int c = 0; c < 4; ++c) L += Lp[(size_t)(rt * 4 + c) * 16 + row];
    const float invL = 1.0f / fmaxf(L, 1e-30f);

    float p[16], wv[16];
#pragma unroll
    for (int k = 0; k < 16; ++k) { p[k] = 0.f; wv[k] = 0.f; }
#pragma unroll
    for (int c = 0; c < 4; ++c) {
        const size_t b = (size_t)(rt * 4 + c) * 4096 + row * 256 + cg * 16;
        u16x8 pa0 = *(const u16x8*)(pacc_b + b);
        u16x8 pa1 = *(const u16x8*)(pacc_b + b + 8);
        u16x8 wa0 = *(const u16x8*)(wacc_b + b);
        u16x8 wa1 = *(const u16x8*)(wacc_b + b + 8);
#pragma unroll
        for (int k = 0; k < 8; ++k) {
            p[k] += bf2f(pa0[k]);  p[k + 8] += bf2f(pa1[k]);
            wv[k] += bf2f(wa0[k]); wv[k + 8] += bf2f(wa1[k]);
        }
    }

    float mx = -3.0e38f;
#pragma unroll
    for (int k = 0; k < 16; ++k) mx = fmaxf(mx, p[k]);
    mx = wmax16(mx);
    float sm = 0.f;
#pragma unroll
    for (int k = 0; k < 16; ++k) { p[k] = __expf(p[k] - mx); sm += p[k]; }
    sm = wsum16(sm);
    const float inv = 1.0f / sm;

    float* orow = out + ((size_t)(rt * 16 + row)) * 256 + cg * 16;
#pragma unroll
    for (int k4 = 0; k4 < 4; ++k4) {
        float4 o;
        float v;
        v = wv[k4*4+0] * invL + p[k4*4+0] * inv; o.x = v > 0.f ? v : __expf(v) - 1.f;
        v = wv[k4*4+1] * invL + p[k4*4+1] * inv; o.y = v > 0.f ? v : __expf(v) - 1.f;
        v = wv[k4*4+2] * invL + p[k4*4+2] * inv; o.z = v > 0.f ? v : __expf(v) - 1.f;
        v = wv[k4*4+3] * invL + p[k4*4+3] * inv; o.w = v > 0.f ? v : __expf(v) - 1.f;
        *(float4*)(orow + k4 * 4) = o;
    }
}

extern "C" void kernel_launch(void* const* d_in, const int* in_sizes, int n_in,
                              void* d_out, int out_size, void* d_ws, size_t ws_size,
                              hipStream_t stream)
{
    const float* h      = (const float*)d_in[0];
    const int*   adj    = (const int*)d_in[1];
    const float* W      = (const float*)d_in[2];
    const float* Wl_w   = (const float*)d_in[3];
    const float* Wl_b   = (const float*)d_in[4];
    const float* Wqkv_w = (const float*)d_in[5];
    const float* Wqkv_b = (const float*)d_in[6];
    const float* a      = (const float*)d_in[7];
    float* out = (float*)d_out;

    char* wsb = (char*)d_ws;
    unsigned short* qh     = (unsigned short*)(wsb + 0);          // 2 MB
    unsigned short* kh     = (unsigned short*)(wsb + 2097152);    // 2 MB
    unsigned short* vth    = (unsigned short*)(wsb + 4194304);    // 2 MB
    unsigned short* wht    = (unsigned short*)(wsb + 6291456);    // 2 MB
    unsigned short* dsum_b = (unsigned short*)(wsb + 8388608);    // 32 MB
    unsigned short* pacc_b = (unsigned short*)(wsb + 41943040);   // 8 MB
    unsigned short* wacc_b = (unsigned short*)(wsb + 50331648);   // 8 MB
    float*          Whb    = (float*)(wsb + 50331648);            // overlay (dead before outer)
    unsigned short* Whi    = (unsigned short*)(wsb + 58720256);   // 256 KB
    unsigned short* Wlo    = Whi + 131072;
    unsigned short* Qhi    = Wlo + 131072;                        // 384 KB
    unsigned short* Qlo    = Qhi + 196608;
    unsigned short* WcThi  = Qlo + 196608;                        // 256 KB
    unsigned short* WcTlo  = WcThi + 131072;
    float*          p1b    = (float*)(wsb + 60555264);
    float*          p2b    = (float*)(wsb + 60571648);
    float*          p2m    = (float*)(wsb + 60588032);
    float*          qn2    = (float*)(wsb + 60592128);
    float*          knp    = (float*)(wsb + 60657664);
    float*          Mb     = (float*)(wsb + 60661760);
    float*          zpart  = (float*)(wsb + 60727296);
    float*          Lp     = (float*)(wsb + 60989440);

    dim3 blk(256);
    wprep<<<dim3(768), blk, 0, stream>>>(W, Wqkv_w, Whi, Wlo, Qhi, Qlo);
    gemm_mfma<3, false><<<dim3(8, 4), blk, 0, stream>>>(
        Wl_w, Whi, Wlo, nullptr, nullptr, WcThi, WcTlo, nullptr, 256, 512, 256);
    gemm_mfma<1, true><<<dim3(4, 64), blk, 0, stream>>>(
        h, WcThi, WcTlo, Wl_b, Whb, wht, nullptr, nullptr, 4096, 256, 512);
    gemm_mfma<2, true><<<dim3(12, 64), blk, 0, stream>>>(
        Whb, Qhi, Qlo, Wqkv_b, nullptr, qh, kh, vth, 4096, 768, 256);
    compute_p<<<dim3(256), blk, 0, stream>>>(Whb, a, p1b, p2b);
    p2max_kernel<<<dim3(1), blk, 0, stream>>>(p2b, p2m);
    norms1<<<dim3(256), blk, 0, stream>>>(qh, kh, qn2, knp);
    norms2<<<dim3(16), blk, 0, stream>>>(qn2, knp, Mb);
    zsum_kernel<<<dim3(1024), blk, 0, stream>>>(qh, kh, Mb, zpart);
    pvds_kernel<<<dim3(1024), blk, 0, stream>>>(qh, kh, vth, Mb, zpart, dsum_b, pacc_b);
    outer_kernel<<<dim3(1024), blk, 0, stream>>>(wht, dsum_b, p1b, p2b, p2m, adj, wacc_b, Lp);
    merge_kernel<<<dim3(256), blk, 0, stream>>>(pacc_b, wacc_b, Lp, out);
}